// Round 10
// baseline (110.675 us; speedup 1.0000x reference)
//
#include <hip/hip_runtime.h>

// Mutihead_Attention: x,y [2,2048,512] f32. Flat-reshape => head-batch hb owns
// contiguous [2048,64] chunk at hb*131072 of each [4096,512] projection.
// scores=QK^T/sqrt(512); mask score<=rowmean; softmax; PV; @o_w^T+o_b.
// rowmean_i = q_i.ksum/2048 (ksum fused in K-proj epilogue).
// R10: (a) attn kv-split across blocks (grid 512, 1024 keys/block; partials
// combine by plain addition -- no running max) + KL single-buffered => LDS
// 80KB => 2 blocks/CU, 4 waves/SIMD (was 2). bf16 O-partials + f32 z into dead
// ws buffers; tiny combine kernel. (b) V-proj / O-proj are fully-plain bf16
// GEMMs (1 MFMA vs 3): plain-V error averages down 1/sqrt(1024) in PV.

typedef unsigned short ushort;
typedef unsigned int uint;

typedef __bf16  bf16x8   __attribute__((ext_vector_type(8)));
typedef float   floatx4  __attribute__((ext_vector_type(4)));
typedef float   floatx16 __attribute__((ext_vector_type(16)));
typedef float   float4v  __attribute__((ext_vector_type(4)));
typedef uint    uint4v   __attribute__((ext_vector_type(4)));
typedef ushort  ushort4v __attribute__((ext_vector_type(4)));

#define MFMA16(a,b,c) __builtin_amdgcn_mfma_f32_16x16x32_bf16((a),(b),(c),0,0,0)
#define MFMA32(a,b,c) __builtin_amdgcn_mfma_f32_32x32x16_bf16((a),(b),(c),0,0,0)

__device__ __forceinline__ float b2f(ushort u){
  union { uint i; float f; } v; v.i = ((uint)u) << 16; return v.f;
}
__device__ __forceinline__ ushort f2b(float f){   // RNE f32->bf16
  union { float f; uint i; } v; v.f = f;
  uint r = v.i + 0x7FFFu + ((v.i >> 16) & 1u);
  return (ushort)(r >> 16);
}
__device__ __forceinline__ void split2(float f, ushort& h, ushort& l){
  h = f2b(f);
  l = f2b(f - b2f(h));
}
__device__ __forceinline__ void gload16(const ushort* g, ushort* l){
  __builtin_amdgcn_global_load_lds(
      (const __attribute__((address_space(1))) unsigned int*)g,
      (__attribute__((address_space(3))) unsigned int*)l, 16, 0, 0);
}

// ---------------------------------------------------------------------------
// One-time f32 -> (hi,lo) bf16 split converters.
// ---------------------------------------------------------------------------
__global__ __launch_bounds__(256) void split_xy(
    const float* __restrict__ x, const float* __restrict__ y,
    ushort* __restrict__ xhi, ushort* __restrict__ xlo,
    ushort* __restrict__ yhi, ushort* __restrict__ ylo)
{
  int idx = blockIdx.x * 256 + threadIdx.x;   // 0 .. 1048575 float4s
  const float* sp; ushort *hp, *lp; int i;
  if (idx < 524288){ sp = x; hp = xhi; lp = xlo; i = idx; }
  else             { sp = y; hp = yhi; lp = ylo; i = idx - 524288; }
  float4v d = ((const float4v*)sp)[i];
  ushort4v h, l;
  #pragma unroll
  for (int j=0;j<4;j++){ ushort hh,ll; split2(d[j],hh,ll); h[j]=hh; l[j]=ll; }
  ((ushort4v*)hp)[i] = h;
  ((ushort4v*)lp)[i] = l;
}

// q_w,k_w split; v_w,o_w plain bf16 only.
__global__ __launch_bounds__(256) void split_w(
    const float* __restrict__ qw, const float* __restrict__ kw,
    const float* __restrict__ vw, const float* __restrict__ ow,
    ushort* __restrict__ qwh, ushort* __restrict__ qwl,
    ushort* __restrict__ kwh, ushort* __restrict__ kwl,
    ushort* __restrict__ vwh, ushort* __restrict__ owh)
{
  int idx = blockIdx.x * 256 + threadIdx.x;   // 0 .. 262143 float4s
  int a = idx >> 16, i = idx & 65535;
  if (a < 2){
    const float* sp = a ? kw : qw;
    ushort *hp = a ? kwh : qwh, *lp = a ? kwl : qwl;
    float4v d = ((const float4v*)sp)[i];
    ushort4v h, l;
    #pragma unroll
    for (int j=0;j<4;j++){ ushort hh,ll; split2(d[j],hh,ll); h[j]=hh; l[j]=ll; }
    ((ushort4v*)hp)[i] = h;
    ((ushort4v*)lp)[i] = l;
  } else {
    const float* sp = (a == 2) ? vw : ow;
    ushort *hp = (a == 2) ? vwh : owh;
    float4v d = ((const float4v*)sp)[i];
    ushort4v h;
    #pragma unroll
    for (int j=0;j<4;j++) h[j] = f2b(d[j]);
    ((ushort4v*)hp)[i] = h;
  }
}

// ---------------------------------------------------------------------------
// C[M,512] = A[M,512] @ B[512,512]^T + bias.
// PREC 2: A,B split bf16 (3 MFMA). PREC 0: A,B plain bf16 (1 MFMA).
// BM=64 BN=64 BK=64, 1-D grid 512 with XCD swizzle (m-panel per XCD).
// OUT_MODE 0: f32. 1: hi/lo bf16. 2: plain bf16. KSUM: fused column sums.
// ---------------------------------------------------------------------------
template<int OUT_MODE, bool KSUM, int PREC>
__global__ __launch_bounds__(256) void proj2(
    const ushort* __restrict__ Ahi, const ushort* __restrict__ Alo,
    const ushort* __restrict__ Bhi, const ushort* __restrict__ Blo,
    const float* __restrict__ bias,
    float* __restrict__ outf, ushort* __restrict__ outhi, ushort* __restrict__ outlo,
    float* __restrict__ ksum_out)
{
  constexpr bool SA = (PREC == 2);
  const int id = blockIdx.x;
  const int m0 = ((id & 7) * 8 + ((id >> 3) & 7)) * 64;
  const int n0 = (id >> 6) * 64;

  __shared__ __align__(16) ushort AH[2][4096];                 // [64][64]
  __shared__ __align__(16) ushort AL[SA?2:1][4096];
  __shared__ __align__(16) ushort BH[2][4096];
  __shared__ __align__(16) ushort BL[SA?2:1][4096];
  __shared__ float cs[64];

  const int t    = threadIdx.x;
  const int lane = t & 63;
  const int w    = t >> 6;
  const int wm   = w >> 1, wn = w & 1;
  const int lr   = lane & 15, lg = lane >> 4;

  const int rl  = lane >> 3;
  const int c8s = (lane & 7) ^ rl;       // pre-swizzled source 16B block
  constexpr int NCH = SA ? 8 : 4;

  auto stage = [&](int buf, int k0){
    #pragma unroll
    for (int j = 0; j < NCH; j++){
      const int c = w * NCH + j;
      if constexpr (SA){
        if (c < 8)
          gload16(Ahi + (size_t)(m0 + c*8 + rl)*512 + k0 + c8s*8, &AH[buf][c*512]);
        else if (c < 16)
          gload16(Alo + (size_t)(m0 + (c-8)*8 + rl)*512 + k0 + c8s*8, &AL[buf][(c-8)*512]);
        else if (c < 24)
          gload16(Bhi + (size_t)(n0 + (c-16)*8 + rl)*512 + k0 + c8s*8, &BH[buf][(c-16)*512]);
        else
          gload16(Blo + (size_t)(n0 + (c-24)*8 + rl)*512 + k0 + c8s*8, &BL[buf][(c-24)*512]);
      } else {
        if (c < 8)
          gload16(Ahi + (size_t)(m0 + c*8 + rl)*512 + k0 + c8s*8, &AH[buf][c*512]);
        else
          gload16(Bhi + (size_t)(n0 + (c-8)*8 + rl)*512 + k0 + c8s*8, &BH[buf][(c-8)*512]);
      }
    }
  };

  floatx4 zf; zf[0]=0.f; zf[1]=0.f; zf[2]=0.f; zf[3]=0.f;
  floatx4 acc[2][2];
  #pragma unroll
  for (int i=0;i<2;i++)
    #pragma unroll
    for (int j=0;j<2;j++) acc[i][j] = zf;

  stage(0, 0);
  __syncthreads();

  int cur = 0;
  for (int it = 0; it < 8; ++it){
    if (it < 7) stage(cur^1, (it+1)*64);

    const ushort* AHc = AH[cur];
    const ushort* ALc = SA ? AL[cur] : nullptr;
    const ushort* BHc = BH[cur];
    const ushort* BLc = SA ? BL[cur] : nullptr;

    #pragma unroll
    for (int ks=0; ks<2; ks++){
      const int xo = ((ks*4 + lg) ^ (lr & 7)) << 3;
      bf16x8 ah[2], al[2], bh[2], bl[2];
      #pragma unroll
      for (int mi=0;mi<2;mi++){
        const int off = (wm*32 + mi*16 + lr)*64 + xo;
        ah[mi] = *(const bf16x8*)&AHc[off];
        if constexpr (SA) al[mi] = *(const bf16x8*)&ALc[off];
      }
      #pragma unroll
      for (int ni=0;ni<2;ni++){
        const int off = (wn*32 + ni*16 + lr)*64 + xo;
        bh[ni] = *(const bf16x8*)&BHc[off];
        if constexpr (SA) bl[ni] = *(const bf16x8*)&BLc[off];
      }
      #pragma unroll
      for (int mi=0;mi<2;mi++)
        #pragma unroll
        for (int ni=0;ni<2;ni++){
          acc[mi][ni] = MFMA16(ah[mi], bh[ni], acc[mi][ni]);
          if constexpr (SA){
            acc[mi][ni] = MFMA16(ah[mi], bl[ni], acc[mi][ni]);
            acc[mi][ni] = MFMA16(al[mi], bh[ni], acc[mi][ni]);
          }
        }
    }
    __syncthreads();
    cur ^= 1;
  }

  // epilogue: D frag -> m = lg*4+r, n = lr
  #pragma unroll
  for (int ni=0;ni<2;ni++){
    const int n = n0 + wn*32 + ni*16 + lr;
    const float bn = bias[n];
    #pragma unroll
    for (int mi=0;mi<2;mi++){
      #pragma unroll
      for (int r=0;r<4;r++){
        const int m = m0 + wm*32 + mi*16 + lg*4 + r;
        const float c = acc[mi][ni][r] + bn;
        const size_t off = (size_t)m*512 + n;
        if (OUT_MODE == 0)      { outf[off] = c; }
        else if (OUT_MODE == 1) { ushort h,l; split2(c,h,l); outhi[off]=h; outlo[off]=l; }
        else                    { outhi[off] = f2b(c); }
      }
    }
  }

  if (KSUM) {
    if (t < 64) cs[t] = 0.f;
    __syncthreads();
    #pragma unroll
    for (int ni=0;ni<2;ni++){
      float s = 0.f;
      #pragma unroll
      for (int mi=0;mi<2;mi++)
        #pragma unroll
        for (int r=0;r<4;r++) s += acc[mi][ni][r];
      atomicAdd(&cs[wn*32 + ni*16 + lr], s);
    }
    __syncthreads();
    if (t < 64){
      const int hb = m0 >> 8;
      atomicAdd(&ksum_out[hb*64 + t], cs[t] + 64.f * bias[n0 + t]);
    }
  }
}

// ---------------------------------------------------------------------------
// vt[hb][d][s] = pv[hb][s][d]  (64x64 LDS-tiled transpose)
// ---------------------------------------------------------------------------
__global__ __launch_bounds__(256) void vtrans(
    const ushort* __restrict__ pv, ushort* __restrict__ vt)
{
  const int hb = blockIdx.y;
  const int s0 = blockIdx.x * 64;
  const size_t cb = (size_t)hb * 131072;
  __shared__ __align__(16) ushort T[64][68];
  const int t = threadIdx.x;
  {
    int s = t >> 2, c = (t & 3) * 16;
    *(uint4v*)&T[s][c]     = *(const uint4v*)&pv[cb + (size_t)(s0+s)*64 + c];
    *(uint4v*)&T[s][c + 8] = *(const uint4v*)&pv[cb + (size_t)(s0+s)*64 + c + 8];
  }
  __syncthreads();
  const int d = t >> 2, sc = (t & 3) * 16;
  ushort buf[16];
  #pragma unroll
  for (int i=0;i<16;i++) buf[i] = T[sc + i][d];
  *(uint4v*)&vt[cb + (size_t)d*2048 + s0 + sc]     = *(const uint4v*)&buf[0];
  *(uint4v*)&vt[cb + (size_t)d*2048 + s0 + sc + 8] = *(const uint4v*)&buf[8];
}

// ---------------------------------------------------------------------------
// Fused attention, kv-split: block = (hb, q0, kv-half of 1024 keys).
// 8 waves = 4 q-groups (32 q, 32x32x16 MFMA swapped QK^T) x 2 kv-sub-halves
// (512 keys = 8 tiles each). LDS 80KB: KH dbuf + VT dbuf + KL single-buffered
// (staged after QK^T behind barrier1) -> 2 blocks/CU, 4 waves/SIMD.
// Partial O (bf16) + z (f32) to global; combine kernel sums & normalizes.
// ---------------------------------------------------------------------------
__device__ __forceinline__ void stage_khvt(
    ushort* khb, ushort* vtb, const ushort* gkhi, const ushort* gvt,
    size_t cb, int kvb, int ws, int l)
{
  const int rsub = l >> 3;
  const int c8   = (l & 7) ^ rsub;
  #pragma unroll
  for (int j = 0; j < 4; j++){
    const int chunk = ws*4 + j;       // 16 x 1KB: 8 KH, 8 VT
    const int a   = chunk >> 3;
    const int sub = chunk & 7;
    const int row = sub*8 + rsub;
    if (a == 0)
      gload16(gkhi + cb + (size_t)(kvb + row)*64 + c8*8, khb + sub*512);
    else
      gload16(gvt  + cb + (size_t)row*2048 + kvb + c8*8, vtb + sub*512);
  }
}
__device__ __forceinline__ void stage_kl(
    ushort* klb, const ushort* gklo, size_t cb, int kvb, int ws, int l)
{
  const int rsub = l >> 3;
  const int c8   = (l & 7) ^ rsub;
  #pragma unroll
  for (int j = 0; j < 2; j++){
    const int sub = ws*2 + j;
    const int row = sub*8 + rsub;
    gload16(gklo + cb + (size_t)(kvb + row)*64 + c8*8, klb + sub*512);
  }
}

__global__ __launch_bounds__(512) void attn_kernel(
    const ushort* __restrict__ qhi, const ushort* __restrict__ qlo,
    const ushort* __restrict__ khi, const ushort* __restrict__ klo,
    const ushort* __restrict__ vt,  const float* __restrict__ ksum,
    ushort* __restrict__ Oa, ushort* __restrict__ Ob,
    float* __restrict__ za, float* __restrict__ zb)
{
  const int id = blockIdx.x;        // [q 4b][kv 1b][hb-lo 1b][xcd 3b] -> 2 hb/XCD
  const int hb = ((id & 7) << 1) | ((id >> 3) & 1);
  const int kv = (id >> 4) & 1;
  const int q0 = (id >> 5) * 128;
  const size_t cb = (size_t)hb * 131072;
  const float C1 = 0.04419417382415922f * 1.44269504088896f;  // NF*log2(e)

  __shared__ __align__(16) ushort SMEM[40960];   // 80KB manual partition
  ushort* KHb = SMEM;            // [half][buf][4096]
  ushort* VTb = SMEM + 16384;    // [half][buf][4096]
  ushort* KLb = SMEM + 32768;    // [half][4096] single-buffered

  const int t = threadIdx.x, l = t & 63, w = t >> 6;
  const int half = w >> 2, ws = w & 3;
  const int lq = l & 31, h = l >> 5;
  const int kbase = kv*1024 + half*512;

  ushort* op = kv ? Ob : Oa;
  float*  zp = kv ? zb : za;

  stage_khvt(KHb + (half*2)*4096, VTb + (half*2)*4096, khi, vt, cb, kbase, ws, l);
  stage_kl(KLb + half*4096, klo, cb, kbase, ws, l);

  // Q frags (swapped-B operand): lane holds Q[q = lq][d = st*16 + h*8 + 0..7]
  union U8 { bf16x8 v; ushort u[8]; };
  U8 qfh[4], qfl[4];
  float part = 0.f;
  #pragma unroll
  for (int st=0; st<4; st++){
    size_t g = cb + (size_t)(q0 + ws*32 + lq)*64 + st*16 + h*8;
    qfh[st].v = *(const bf16x8*)&qhi[g];
    qfl[st].v = *(const bf16x8*)&qlo[g];
    float4v k0 = *(const float4v*)&ksum[hb*64 + st*16 + h*8];
    float4v k1 = *(const float4v*)&ksum[hb*64 + st*16 + h*8 + 4];
    #pragma unroll
    for (int j=0;j<4;j++) part += (b2f(qfh[st].u[j])   + b2f(qfl[st].u[j]))   * k0[j];
    #pragma unroll
    for (int j=0;j<4;j++) part += (b2f(qfh[st].u[4+j]) + b2f(qfl[st].u[4+j])) * k1[j];
  }
  part += __shfl_xor(part, 32);            // both d-halves
  const float rm = part * (1.f/2048.f);    // raw row mean for q = lq
  const float nrmc = -rm * C1;

  floatx16 O0 = {0,0,0,0,0,0,0,0,0,0,0,0,0,0,0,0};
  floatx16 O1 = O0;
  float za_r = 0.f, zb_r = 0.f;

  __syncthreads();                          // tile 0 fully staged

  for (int kt = 0; kt < 8; kt++){
    const int cur = kt & 1;
    if (kt + 1 < 8)
      stage_khvt(KHb + (half*2 + (cur^1))*4096, VTb + (half*2 + (cur^1))*4096,
                 khi, vt, cb, kbase + (kt+1)*64, ws, l);

    const ushort* KHc = KHb + (half*2 + cur)*4096;
    const ushort* KLc = KLb + half*4096;
    const ushort* VTc = VTb + (half*2 + cur)*4096;

    // QK^T swapped: s_g[key][q] (q = lq lane-local)
    floatx16 s0 = {0,0,0,0,0,0,0,0,0,0,0,0,0,0,0,0};
    floatx16 s1 = s0;
    #pragma unroll
    for (int st=0; st<4; st++){
      const int xo = (((st*2 + h) ^ (lq & 7)) << 3);
      bf16x8 kh0 = *(const bf16x8*)&KHc[(lq     )*64 + xo];
      bf16x8 kl0 = *(const bf16x8*)&KLc[(lq     )*64 + xo];
      bf16x8 kh1 = *(const bf16x8*)&KHc[(32 + lq)*64 + xo];
      bf16x8 kl1 = *(const bf16x8*)&KLc[(32 + lq)*64 + xo];
      s0 = MFMA32(kh0, qfh[st].v, s0);
      s1 = MFMA32(kh1, qfh[st].v, s1);
      s0 = MFMA32(kh0, qfl[st].v, s0);
      s1 = MFMA32(kh1, qfl[st].v, s1);
      s0 = MFMA32(kl0, qfh[st].v, s0);
      s1 = MFMA32(kl1, qfh[st].v, s1);
    }
    __syncthreads();                 // barrier1: all waves done reading KL
    if (kt + 1 < 8)
      stage_kl(KLb + half*4096, klo, cb, kbase + (kt+1)*64, ws, l);

    // mask + exp (fma + exp2 + cndmask), z from unrounded p
    #pragma unroll
    for (int r=0;r<16;r++){
      float t0 = __builtin_fmaf(s0[r], C1, nrmc);
      float t1 = __builtin_fmaf(s1[r], C1, nrmc);
      float e0 = __builtin_amdgcn_exp2f(t0);
      float e1 = __builtin_amdgcn_exp2f(t1);
      e0 = (t0 > 0.f) ? e0 : 0.f;
      e1 = (t1 > 0.f) ? e1 : 0.f;
      za_r += e0; zb_r += e1;
      s0[r] = e0; s1[r] = e1;
    }

    // pack P into PV A-frags (cvt_pk RNE + permlane32_swap; verified layout)
    bf16x8 pa[4];
    #pragma unroll
    for (int g=0; g<2; g++){
      const floatx16& sp = g ? s1 : s0;
      #pragma unroll
      for (int sg=0; sg<2; sg++){
        uint X0,X1,X2,X3;
        asm("v_cvt_pk_bf16_f32 %0, %1, %2" : "=v"(X0) : "v"(sp[sg*8+0]), "v"(sp[sg*8+1]));
        asm("v_cvt_pk_bf16_f32 %0, %1, %2" : "=v"(X1) : "v"(sp[sg*8+2]), "v"(sp[sg*8+3]));
        asm("v_cvt_pk_bf16_f32 %0, %1, %2" : "=v"(X2) : "v"(sp[sg*8+4]), "v"(sp[sg*8+5]));
        asm("v_cvt_pk_bf16_f32 %0, %1, %2" : "=v"(X3) : "v"(sp[sg*8+6]), "v"(sp[sg*8+7]));
        asm("v_permlane32_swap_b32 %0, %1" : "+v"(X0), "+v"(X2));
        asm("v_permlane32_swap_b32 %0, %1" : "+v"(X1), "+v"(X3));
        union { uint u[4]; bf16x8 v; } pu;
        pu.u[0]=X0; pu.u[1]=X1; pu.u[2]=X2; pu.u[3]=X3;
        pa[g*2+sg] = pu.v;
      }
    }

    // PV: O[q][d] += P[q][k] V[k][d]
    #pragma unroll
    for (int s4=0; s4<4; s4++){
      const int xo = (((s4*2 + h) ^ (lq & 7)) << 3);
      bf16x8 vf0 = *(const bf16x8*)&VTc[(lq     )*64 + xo];
      bf16x8 vf1 = *(const bf16x8*)&VTc[(32 + lq)*64 + xo];
      O0 = MFMA32(pa[s4], vf0, O0);
      O1 = MFMA32(pa[s4], vf1, O1);
    }

    __syncthreads();                 // barrier2: tile reads done + stages drained
  }

  // cross-sub-half combine in LDS, then partial (O,z) to global (no divide)
  float zacc = za_r + zb_r;
  zacc += __shfl_xor(zacc, 32);
  float* CB = (float*)SMEM;                 // 20480 floats available
  const int ci = (ws*64 + l)*34;
  if (half == 1){
    #pragma unroll
    for (int i=0;i<16;i++){ CB[ci+i] = O0[i]; CB[ci+16+i] = O1[i]; }
    CB[ci+32] = zacc;
  }
  __syncthreads();
  if (half == 0){
    const float zsum = zacc + CB[ci+32];
    if (h == 0) zp[hb*2048 + q0 + ws*32 + l] = zsum;
    #pragma unroll
    for (int r=0;r<16;r++){ O0[r] += CB[ci+r]; O1[r] += CB[ci+16+r]; }
    #pragma unroll
    for (int r=0;r<16;r++){
      const int crow = (r&3) + ((r>>2)<<3) + (h<<2);
      const int q = q0 + ws*32 + crow;
      const size_t base = cb + (size_t)q*64 + lq;
      op[base]      = f2b(O0[r]);
      op[base + 32] = f2b(O1[r]);
    }
  }
}

// ---------------------------------------------------------------------------
// attno[r][d] = (Oa + Ob) / (za + zb), bf16 out. r = hb*2048+q (linear).
// ---------------------------------------------------------------------------
__global__ __launch_bounds__(256) void combine_kernel(
    const ushort* __restrict__ Oa, const ushort* __restrict__ Ob,
    const float* __restrict__ za, const float* __restrict__ zb,
    ushort* __restrict__ attno)
{
  const int idx = blockIdx.x * 256 + threadIdx.x;   // 8-elem chunk, 262144 total
  const int q = idx >> 3;
  const float zi = 1.f / (za[q] + zb[q]);
  uint4v av = ((const uint4v*)Oa)[idx];
  uint4v bv = ((const uint4v*)Ob)[idx];
  uint4v ov;
  #pragma unroll
  for (int j=0;j<4;j++){
    float lo = (b2f((ushort)(av[j] & 0xffff)) + b2f((ushort)(bv[j] & 0xffff))) * zi;
    float hi = (b2f((ushort)(av[j] >> 16))    + b2f((ushort)(bv[j] >> 16)))    * zi;
    ov[j] = (uint)f2b(lo) | ((uint)f2b(hi) << 16);
  }
  ((uint4v*)attno)[idx] = ov;
}

// ---------------------------------------------------------------------------
extern "C" void kernel_launch(void* const* d_in, const int* in_sizes, int n_in,
                              void* d_out, int out_size, void* d_ws, size_t ws_size,
                              hipStream_t stream)
{
  const float* x   = (const float*)d_in[0];
  const float* y   = (const float*)d_in[1];
  const float* q_w = (const float*)d_in[2];
  const float* q_b = (const float*)d_in[3];
  const float* k_w = (const float*)d_in[4];
  const float* k_b = (const float*)d_in[5];
  const float* v_w = (const float*)d_in[6];
  const float* v_b = (const float*)d_in[7];
  const float* o_w = (const float*)d_in[8];
  const float* o_b = (const float*)d_in[9];

  const size_t NE = 4096ull * 512;     // 2,097,152
  const size_t WN = 512ull * 512;      // 262,144
  ushort* p = (ushort*)d_ws;
  ushort* pq_hi = p;                   // 5 x NE: projections
  ushort* pq_lo = pq_hi + NE;
  ushort* pk_hi = pq_lo + NE;
  ushort* pk_lo = pk_hi + NE;
  ushort* pv    = pk_lo + NE;
  ushort* xhi   = pv + NE;             // 4 x NE: split inputs
  ushort* xlo   = xhi + NE;
  ushort* yhi   = xlo + NE;
  ushort* ylo   = yhi + NE;
  ushort* vtg   = xhi;                 // alias: xhi dead after Q-proj
  ushort* attno = xlo;                 // alias: xlo dead after Q-proj
  ushort* Oa    = pv;                  // alias: pv dead after vtrans
  ushort* Ob    = yhi;                 // alias: yhi dead after K/V-proj
  float*  za    = (float*)ylo;         // alias: ylo dead after K/V-proj
  float*  zb    = za + 32768;
  ushort* qwh = ylo + NE;              // split weights (+ plain v/o)
  ushort* qwl = qwh + WN;
  ushort* kwh = qwl + WN;
  ushort* kwl = kwh + WN;
  ushort* vwh = kwl + WN;
  ushort* owh = vwh + WN;
  float*  ksumb = (float*)(owh + WN);

  hipMemsetAsync(ksumb, 0, 16 * 64 * sizeof(float), stream);

  split_xy<<<4096, 256, 0, stream>>>(x, y, xhi, xlo, yhi, ylo);
  split_w <<<1024, 256, 0, stream>>>(q_w, k_w, v_w, o_w,
                                     qwh, qwl, kwh, kwl, vwh, owh);

  proj2<1,false,2><<<512, 256, 0, stream>>>(xhi, xlo, qwh, qwl, q_b, nullptr, pq_hi, pq_lo, nullptr);
  proj2<1,true ,2><<<512, 256, 0, stream>>>(yhi, ylo, kwh, kwl, k_b, nullptr, pk_hi, pk_lo, ksumb);
  proj2<2,false,0><<<512, 256, 0, stream>>>(yhi, nullptr, vwh, nullptr, v_b, nullptr, pv, nullptr, nullptr);
  vtrans<<<dim3(32,16), 256, 0, stream>>>(pv, vtg);
  attn_kernel<<<512, 512, 0, stream>>>(pq_hi, pq_lo, pk_hi, pk_lo, vtg, ksumb,
                                       Oa, Ob, za, zb);
  combine_kernel<<<1024, 256, 0, stream>>>(Oa, Ob, za, zb, attno);
  proj2<0,false,0><<<512, 256, 0, stream>>>(attno, nullptr, owh, nullptr, o_b, (float*)d_out, nullptr, nullptr, nullptr);
}

// Round 11
// 107.345 us; speedup vs baseline: 1.0310x; 1.0310x over previous
//
#include <hip/hip_runtime.h>

// Mutihead_Attention: x,y [2,2048,512] f32. Flat-reshape => head-batch hb owns
// contiguous [2048,64] chunk at hb*131072 of each [4096,512] projection.
// scores=QK^T/sqrt(512); mask score<=rowmean; softmax; PV; @o_w^T+o_b.
// rowmean_i = q_i.ksum/2048 (ksum fused in K-proj epilogue).
// R11: (a) attn LDS 80->64KB (VT single-buffered like KL; staged top-of-iter,
// visible after barrier1's vmcnt drain) => 2 blocks/CU truly co-resident
// (R10's 80KBx2=160KB exactly never co-scheduled; occupancy stuck 19%).
// (b) dispatch diet 10->6: split_all (xy+weights), proj_qkv (Q/K/V one grid),
// combine FUSED into O-proj A-staging ((Oa+Ob)*zi on the fly, swizzled
// ds_write) -- small GEMMs proved launch/staging-bound, not MFMA-bound.

typedef unsigned short ushort;
typedef unsigned int uint;

typedef __bf16  bf16x8   __attribute__((ext_vector_type(8)));
typedef float   floatx4  __attribute__((ext_vector_type(4)));
typedef float   floatx16 __attribute__((ext_vector_type(16)));
typedef float   float4v  __attribute__((ext_vector_type(4)));
typedef uint    uint4v   __attribute__((ext_vector_type(4)));
typedef ushort  ushort4v __attribute__((ext_vector_type(4)));

#define MFMA16(a,b,c) __builtin_amdgcn_mfma_f32_16x16x32_bf16((a),(b),(c),0,0,0)
#define MFMA32(a,b,c) __builtin_amdgcn_mfma_f32_32x32x16_bf16((a),(b),(c),0,0,0)

__device__ __forceinline__ float b2f(ushort u){
  union { uint i; float f; } v; v.i = ((uint)u) << 16; return v.f;
}
__device__ __forceinline__ ushort f2b(float f){   // RNE f32->bf16
  union { float f; uint i; } v; v.f = f;
  uint r = v.i + 0x7FFFu + ((v.i >> 16) & 1u);
  return (ushort)(r >> 16);
}
__device__ __forceinline__ void split2(float f, ushort& h, ushort& l){
  h = f2b(f);
  l = f2b(f - b2f(h));
}
__device__ __forceinline__ void gload16(const ushort* g, ushort* l){
  __builtin_amdgcn_global_load_lds(
      (const __attribute__((address_space(1))) unsigned int*)g,
      (__attribute__((address_space(3))) unsigned int*)l, 16, 0, 0);
}

// ---------------------------------------------------------------------------
// One-time f32 -> bf16 converters, all inputs in one launch.
// idx < 1048576: x,y -> hi/lo split. Else: q_w,k_w -> split; v_w,o_w -> plain.
// ---------------------------------------------------------------------------
__global__ __launch_bounds__(256) void split_all(
    const float* __restrict__ x, const float* __restrict__ y,
    const float* __restrict__ qw, const float* __restrict__ kw,
    const float* __restrict__ vw, const float* __restrict__ ow,
    ushort* __restrict__ xhi, ushort* __restrict__ xlo,
    ushort* __restrict__ yhi, ushort* __restrict__ ylo,
    ushort* __restrict__ qwh, ushort* __restrict__ qwl,
    ushort* __restrict__ kwh, ushort* __restrict__ kwl,
    ushort* __restrict__ vwh, ushort* __restrict__ owh)
{
  int idx = blockIdx.x * 256 + threadIdx.x;       // 1,310,720 float4s total
  if (idx < 1048576){
    const float* sp; ushort *hp, *lp; int i;
    if (idx < 524288){ sp = x; hp = xhi; lp = xlo; i = idx; }
    else             { sp = y; hp = yhi; lp = ylo; i = idx - 524288; }
    float4v d = ((const float4v*)sp)[i];
    ushort4v h, l;
    #pragma unroll
    for (int j=0;j<4;j++){ ushort hh,ll; split2(d[j],hh,ll); h[j]=hh; l[j]=ll; }
    ((ushort4v*)hp)[i] = h;
    ((ushort4v*)lp)[i] = l;
  } else {
    int k = idx - 1048576;                        // 0..262143
    int a = k >> 16, i = k & 65535;
    if (a < 2){
      const float* sp = a ? kw : qw;
      ushort *hp = a ? kwh : qwh, *lp = a ? kwl : qwl;
      float4v d = ((const float4v*)sp)[i];
      ushort4v h, l;
      #pragma unroll
      for (int j=0;j<4;j++){ ushort hh,ll; split2(d[j],hh,ll); h[j]=hh; l[j]=ll; }
      ((ushort4v*)hp)[i] = h;
      ((ushort4v*)lp)[i] = l;
    } else {
      const float* sp = (a == 2) ? vw : ow;
      ushort *hp = (a == 2) ? vwh : owh;
      float4v d = ((const float4v*)sp)[i];
      ushort4v h;
      #pragma unroll
      for (int j=0;j<4;j++) h[j] = f2b(d[j]);
      ((ushort4v*)hp)[i] = h;
    }
  }
}

// ---------------------------------------------------------------------------
// Q/K/V projections in ONE dispatch. grid 1536: seg = id>>9 (0=Q,1=K,2=V).
// seg 0/1: split A x split B (3 MFMA), hi/lo out. seg 2: plain (1 MFMA), bf16.
// BM=64 BN=64 BK=64, XCD swizzle on low 9 bits, dbuf, gload_lds(16),
// row&7 XOR swizzle. K-seg fuses ksum column sums.
// ---------------------------------------------------------------------------
__global__ __launch_bounds__(256) void proj_qkv(
    const ushort* __restrict__ xhi, const ushort* __restrict__ xlo,
    const ushort* __restrict__ yhi, const ushort* __restrict__ ylo,
    const ushort* __restrict__ qwh, const ushort* __restrict__ qwl,
    const ushort* __restrict__ kwh, const ushort* __restrict__ kwl,
    const ushort* __restrict__ vwh,
    const float* __restrict__ q_b, const float* __restrict__ k_b,
    const float* __restrict__ v_b,
    ushort* __restrict__ pq_hi, ushort* __restrict__ pq_lo,
    ushort* __restrict__ pk_hi, ushort* __restrict__ pk_lo,
    ushort* __restrict__ pv, float* __restrict__ ksum_out)
{
  const int seg = blockIdx.x >> 9;
  const int id  = blockIdx.x & 511;
  const int m0 = ((id & 7) * 8 + ((id >> 3) & 7)) * 64;
  const int n0 = (id >> 6) * 64;
  const bool split = (seg < 2);

  const ushort* Ahi = (seg == 0) ? xhi : yhi;
  const ushort* Alo = (seg == 0) ? xlo : ylo;
  const ushort* Bhi = (seg == 0) ? qwh : ((seg == 1) ? kwh : vwh);
  const ushort* Blo = (seg == 0) ? qwl : kwl;
  const float*  bias = (seg == 0) ? q_b : ((seg == 1) ? k_b : v_b);
  ushort* outhi = (seg == 0) ? pq_hi : ((seg == 1) ? pk_hi : pv);
  ushort* outlo = (seg == 0) ? pq_lo : pk_lo;

  __shared__ __align__(16) ushort AH[2][4096];                 // [64][64]
  __shared__ __align__(16) ushort AL[2][4096];
  __shared__ __align__(16) ushort BH[2][4096];
  __shared__ __align__(16) ushort BL[2][4096];
  __shared__ float cs[64];

  const int t    = threadIdx.x;
  const int lane = t & 63;
  const int w    = t >> 6;
  const int wm   = w >> 1, wn = w & 1;
  const int lr   = lane & 15, lg = lane >> 4;

  const int rl  = lane >> 3;
  const int c8s = (lane & 7) ^ rl;       // pre-swizzled source 16B block

  auto stage = [&](int buf, int k0){
    if (split){
      #pragma unroll
      for (int j = 0; j < 8; j++){
        const int c = w * 8 + j;
        if (c < 8)
          gload16(Ahi + (size_t)(m0 + c*8 + rl)*512 + k0 + c8s*8, &AH[buf][c*512]);
        else if (c < 16)
          gload16(Alo + (size_t)(m0 + (c-8)*8 + rl)*512 + k0 + c8s*8, &AL[buf][(c-8)*512]);
        else if (c < 24)
          gload16(Bhi + (size_t)(n0 + (c-16)*8 + rl)*512 + k0 + c8s*8, &BH[buf][(c-16)*512]);
        else
          gload16(Blo + (size_t)(n0 + (c-24)*8 + rl)*512 + k0 + c8s*8, &BL[buf][(c-24)*512]);
      }
    } else {
      #pragma unroll
      for (int j = 0; j < 4; j++){
        const int c = w * 4 + j;
        if (c < 8)
          gload16(Ahi + (size_t)(m0 + c*8 + rl)*512 + k0 + c8s*8, &AH[buf][c*512]);
        else
          gload16(Bhi + (size_t)(n0 + (c-8)*8 + rl)*512 + k0 + c8s*8, &BH[buf][(c-8)*512]);
      }
    }
  };

  floatx4 zf; zf[0]=0.f; zf[1]=0.f; zf[2]=0.f; zf[3]=0.f;
  floatx4 acc[2][2];
  #pragma unroll
  for (int i=0;i<2;i++)
    #pragma unroll
    for (int j=0;j<2;j++) acc[i][j] = zf;

  stage(0, 0);
  __syncthreads();

  int cur = 0;
  for (int it = 0; it < 8; ++it){
    if (it < 7) stage(cur^1, (it+1)*64);

    #pragma unroll
    for (int ks=0; ks<2; ks++){
      const int xo = ((ks*4 + lg) ^ (lr & 7)) << 3;
      bf16x8 ah[2], al[2], bh[2], bl[2];
      #pragma unroll
      for (int mi=0;mi<2;mi++){
        const int off = (wm*32 + mi*16 + lr)*64 + xo;
        ah[mi] = *(const bf16x8*)&AH[cur][off];
        if (split) al[mi] = *(const bf16x8*)&AL[cur][off];
      }
      #pragma unroll
      for (int ni=0;ni<2;ni++){
        const int off = (wn*32 + ni*16 + lr)*64 + xo;
        bh[ni] = *(const bf16x8*)&BH[cur][off];
        if (split) bl[ni] = *(const bf16x8*)&BL[cur][off];
      }
      #pragma unroll
      for (int mi=0;mi<2;mi++)
        #pragma unroll
        for (int ni=0;ni<2;ni++){
          acc[mi][ni] = MFMA16(ah[mi], bh[ni], acc[mi][ni]);
          if (split){
            acc[mi][ni] = MFMA16(ah[mi], bl[ni], acc[mi][ni]);
            acc[mi][ni] = MFMA16(al[mi], bh[ni], acc[mi][ni]);
          }
        }
    }
    __syncthreads();
    cur ^= 1;
  }

  // epilogue: D frag -> m = lg*4+r, n = lr
  #pragma unroll
  for (int ni=0;ni<2;ni++){
    const int n = n0 + wn*32 + ni*16 + lr;
    const float bn = bias[n];
    #pragma unroll
    for (int mi=0;mi<2;mi++){
      #pragma unroll
      for (int r=0;r<4;r++){
        const int m = m0 + wm*32 + mi*16 + lg*4 + r;
        const float c = acc[mi][ni][r] + bn;
        const size_t off = (size_t)m*512 + n;
        if (split){ ushort h,l; split2(c,h,l); outhi[off]=h; outlo[off]=l; }
        else      { outhi[off] = f2b(c); }
      }
    }
  }

  if (seg == 1) {
    if (t < 64) cs[t] = 0.f;
    __syncthreads();
    #pragma unroll
    for (int ni=0;ni<2;ni++){
      float s = 0.f;
      #pragma unroll
      for (int mi=0;mi<2;mi++)
        #pragma unroll
        for (int r=0;r<4;r++) s += acc[mi][ni][r];
      atomicAdd(&cs[wn*32 + ni*16 + lr], s);
    }
    __syncthreads();
    if (t < 64){
      const int hb = m0 >> 8;
      atomicAdd(&ksum_out[hb*64 + t], cs[t] + 64.f * bias[n0 + t]);
    }
  }
}

// ---------------------------------------------------------------------------
// vt[hb][d][s] = pv[hb][s][d]  (64x64 LDS-tiled transpose)
// ---------------------------------------------------------------------------
__global__ __launch_bounds__(256) void vtrans(
    const ushort* __restrict__ pv, ushort* __restrict__ vt)
{
  const int hb = blockIdx.y;
  const int s0 = blockIdx.x * 64;
  const size_t cb = (size_t)hb * 131072;
  __shared__ __align__(16) ushort T[64][68];
  const int t = threadIdx.x;
  {
    int s = t >> 2, c = (t & 3) * 16;
    *(uint4v*)&T[s][c]     = *(const uint4v*)&pv[cb + (size_t)(s0+s)*64 + c];
    *(uint4v*)&T[s][c + 8] = *(const uint4v*)&pv[cb + (size_t)(s0+s)*64 + c + 8];
  }
  __syncthreads();
  const int d = t >> 2, sc = (t & 3) * 16;
  ushort buf[16];
  #pragma unroll
  for (int i=0;i<16;i++) buf[i] = T[sc + i][d];
  *(uint4v*)&vt[cb + (size_t)d*2048 + s0 + sc]     = *(const uint4v*)&buf[0];
  *(uint4v*)&vt[cb + (size_t)d*2048 + s0 + sc + 8] = *(const uint4v*)&buf[8];
}

// ---------------------------------------------------------------------------
// Fused attention, kv-split, 64KB LDS: KH dbuf (32KB) + VT single (16KB) +
// KL single (16KB) => 2 blocks/CU. VT(kt) staged at top of iter kt (PV(kt-1)
// finished at barrier2(kt-1)), visible at PV(kt) via barrier1's vmcnt drain.
// 8 waves = 4 q-groups (32 q, 32x32x16 swapped QK^T) x 2 kv-sub-halves.
// Partial O (bf16) + z (f32) to global; combine fused into O-proj.
// ---------------------------------------------------------------------------
__device__ __forceinline__ void stage_kh(
    ushort* dst, const ushort* gk, size_t cb, int kvb, int ws, int l)
{
  const int rsub = l >> 3;
  const int c8   = (l & 7) ^ rsub;
  #pragma unroll
  for (int j = 0; j < 2; j++){
    const int sub = ws*2 + j;
    const int row = sub*8 + rsub;
    gload16(gk + cb + (size_t)(kvb + row)*64 + c8*8, dst + sub*512);
  }
}
__device__ __forceinline__ void stage_vt(
    ushort* dst, const ushort* gvt, size_t cb, int kvb, int ws, int l)
{
  const int rsub = l >> 3;
  const int c8   = (l & 7) ^ rsub;
  #pragma unroll
  for (int j = 0; j < 2; j++){
    const int sub = ws*2 + j;
    const int row = sub*8 + rsub;           // d-index
    gload16(gvt + cb + (size_t)row*2048 + kvb + c8*8, dst + sub*512);
  }
}

__global__ __launch_bounds__(512) void attn_kernel(
    const ushort* __restrict__ qhi, const ushort* __restrict__ qlo,
    const ushort* __restrict__ khi, const ushort* __restrict__ klo,
    const ushort* __restrict__ vt,  const float* __restrict__ ksum,
    ushort* __restrict__ Oa, ushort* __restrict__ Ob,
    float* __restrict__ za, float* __restrict__ zb)
{
  const int id = blockIdx.x;        // [q 4b][kv 1b][hb-lo 1b][xcd 3b]
  const int hb = ((id & 7) << 1) | ((id >> 3) & 1);
  const int kv = (id >> 4) & 1;
  const int q0 = (id >> 5) * 128;
  const size_t cb = (size_t)hb * 131072;
  const float C1 = 0.04419417382415922f * 1.44269504088896f;  // NF*log2(e)

  __shared__ __align__(16) ushort SMEM[32768];   // 64KB manual partition
  // KH: (half*2+buf)*4096 ; VT: 16384 + half*4096 ; KL: 24576 + half*4096

  const int t = threadIdx.x, l = t & 63, w = t >> 6;
  const int half = w >> 2, ws = w & 3;
  const int lq = l & 31, h = l >> 5;
  const int kbase = kv*1024 + half*512;

  ushort* op = kv ? Ob : Oa;
  float*  zp = kv ? zb : za;

  ushort* KH0 = SMEM + (half*2)*4096;
  ushort* KH1 = SMEM + (half*2+1)*4096;
  ushort* VTB = SMEM + 16384 + half*4096;
  ushort* KLB = SMEM + 24576 + half*4096;

  stage_kh(KH0, khi, cb, kbase, ws, l);
  stage_kh(KLB, klo, cb, kbase, ws, l);

  // Q frags (swapped-B operand): lane holds Q[q = lq][d = st*16 + h*8 + 0..7]
  union U8 { bf16x8 v; ushort u[8]; };
  U8 qfh[4], qfl[4];
  float part = 0.f;
  #pragma unroll
  for (int st=0; st<4; st++){
    size_t g = cb + (size_t)(q0 + ws*32 + lq)*64 + st*16 + h*8;
    qfh[st].v = *(const bf16x8*)&qhi[g];
    qfl[st].v = *(const bf16x8*)&qlo[g];
    float4v k0 = *(const float4v*)&ksum[hb*64 + st*16 + h*8];
    float4v k1 = *(const float4v*)&ksum[hb*64 + st*16 + h*8 + 4];
    #pragma unroll
    for (int j=0;j<4;j++) part += (b2f(qfh[st].u[j])   + b2f(qfl[st].u[j]))   * k0[j];
    #pragma unroll
    for (int j=0;j<4;j++) part += (b2f(qfh[st].u[4+j]) + b2f(qfl[st].u[4+j])) * k1[j];
  }
  part += __shfl_xor(part, 32);            // both d-halves
  const float rm = part * (1.f/2048.f);    // raw row mean for q = lq
  const float nrmc = -rm * C1;

  floatx16 O0 = {0,0,0,0,0,0,0,0,0,0,0,0,0,0,0,0};
  floatx16 O1 = O0;
  float za_r = 0.f, zb_r = 0.f;

  __syncthreads();                          // KH(0), KL(0) staged

  for (int kt = 0; kt < 8; kt++){
    ushort* KHc = (kt & 1) ? KH1 : KH0;
    ushort* KHn = (kt & 1) ? KH0 : KH1;
    if (kt + 1 < 8) stage_kh(KHn, khi, cb, kbase + (kt+1)*64, ws, l);
    stage_vt(VTB, vt, cb, kbase + kt*64, ws, l);   // for THIS iter's PV

    // QK^T swapped: s_g[key][q] (q = lq lane-local)
    floatx16 s0 = {0,0,0,0,0,0,0,0,0,0,0,0,0,0,0,0};
    floatx16 s1 = s0;
    #pragma unroll
    for (int st=0; st<4; st++){
      const int xo = (((st*2 + h) ^ (lq & 7)) << 3);
      bf16x8 kh0 = *(const bf16x8*)&KHc[(lq     )*64 + xo];
      bf16x8 kl0 = *(const bf16x8*)&KLB[(lq     )*64 + xo];
      bf16x8 kh1 = *(const bf16x8*)&KHc[(32 + lq)*64 + xo];
      bf16x8 kl1 = *(const bf16x8*)&KLB[(32 + lq)*64 + xo];
      s0 = MFMA32(kh0, qfh[st].v, s0);
      s1 = MFMA32(kh1, qfh[st].v, s1);
      s0 = MFMA32(kh0, qfl[st].v, s0);
      s1 = MFMA32(kh1, qfl[st].v, s1);
      s0 = MFMA32(kl0, qfh[st].v, s0);
      s1 = MFMA32(kl1, qfh[st].v, s1);
    }
    __syncthreads();          // barrier1: KL reads done; VT(kt) drained
    if (kt + 1 < 8) stage_kh(KLB, klo, cb, kbase + (kt+1)*64, ws, l);

    // mask + exp (fma + exp2 + cndmask), z from unrounded p
    #pragma unroll
    for (int r=0;r<16;r++){
      float t0 = __builtin_fmaf(s0[r], C1, nrmc);
      float t1 = __builtin_fmaf(s1[r], C1, nrmc);
      float e0 = __builtin_amdgcn_exp2f(t0);
      float e1 = __builtin_amdgcn_exp2f(t1);
      e0 = (t0 > 0.f) ? e0 : 0.f;
      e1 = (t1 > 0.f) ? e1 : 0.f;
      za_r += e0; zb_r += e1;
      s0[r] = e0; s1[r] = e1;
    }

    // pack P into PV A-frags (cvt_pk RNE + permlane32_swap; verified layout)
    bf16x8 pa[4];
    #pragma unroll
    for (int g=0; g<2; g++){
      const floatx16& sp = g ? s1 : s0;
      #pragma unroll
      for (int sg=0; sg<2; sg++){
        uint X0,X1,X2,X3;
        asm("v_cvt_pk_bf16_f32 %0, %1, %2" : "=v"(X0) : "v"(sp[sg*8+0]), "v"(sp[sg*8+1]));
        asm("v_cvt_pk_bf16_f32 %0, %1, %2" : "=v"(X1) : "v"(sp[sg*8+2]), "v"(sp[sg*8+3]));
        asm("v_cvt_pk_bf16_f32 %0, %1, %2" : "=v"(X2) : "v"(sp[sg*8+4]), "v"(sp[sg*8+5]));
        asm("v_cvt_pk_bf16_f32 %0, %1, %2" : "=v"(X3) : "v"(sp[sg*8+6]), "v"(sp[sg*8+7]));
        asm("v_permlane32_swap_b32 %0, %1" : "+v"(X0), "+v"(X2));
        asm("v_permlane32_swap_b32 %0, %1" : "+v"(X1), "+v"(X3));
        union { uint u[4]; bf16x8 v; } pu;
        pu.u[0]=X0; pu.u[1]=X1; pu.u[2]=X2; pu.u[3]=X3;
        pa[g*2+sg] = pu.v;
      }
    }

    // PV: O[q][d] += P[q][k] V[k][d]   (VT staged this iter, drained @barrier1)
    #pragma unroll
    for (int s4=0; s4<4; s4++){
      const int xo = (((s4*2 + h) ^ (lq & 7)) << 3);
      bf16x8 vf0 = *(const bf16x8*)&VTB[(lq     )*64 + xo];
      bf16x8 vf1 = *(const bf16x8*)&VTB[(32 + lq)*64 + xo];
      O0 = MFMA32(pa[s4], vf0, O0);
      O1 = MFMA32(pa[s4], vf1, O1);
    }

    __syncthreads();          // barrier2: VT/KH reads done; KL(kt+1) drained
  }

  // cross-sub-half combine in LDS, then partial (O,z) to global (no divide)
  float zacc = za_r + zb_r;
  zacc += __shfl_xor(zacc, 32);
  float* CB = (float*)SMEM;
  const int ci = (ws*64 + l)*34;
  if (half == 1){
    #pragma unroll
    for (int i=0;i<16;i++){ CB[ci+i] = O0[i]; CB[ci+16+i] = O1[i]; }
    CB[ci+32] = zacc;
  }
  __syncthreads();
  if (half == 0){
    const float zsum = zacc + CB[ci+32];
    if (h == 0) zp[hb*2048 + q0 + ws*32 + l] = zsum;
    #pragma unroll
    for (int r=0;r<16;r++){ O0[r] += CB[ci+r]; O1[r] += CB[ci+16+r]; }
    #pragma unroll
    for (int r=0;r<16;r++){
      const int crow = (r&3) + ((r>>2)<<3) + (h<<2);
      const int q = q0 + ws*32 + crow;
      const size_t base = cb + (size_t)q*64 + lq;
      op[base]      = f2b(O0[r]);
      op[base + 32] = f2b(O1[r]);
    }
  }
}

// ---------------------------------------------------------------------------
// O-projection with FUSED combine: A[m][k] = (Oa+Ob)[m][k] / z(m,k-block),
// register-staged + swizzled ds_write (B via gload_lds). out f32 + o_b.
// z index: q = ((m&255)*8 + k/64), zq = (m>>8)*2048 + q (constant per iter).
// ---------------------------------------------------------------------------
__global__ __launch_bounds__(256) void proj_out(
    const ushort* __restrict__ Oa, const ushort* __restrict__ Ob,
    const float* __restrict__ za, const float* __restrict__ zb,
    const ushort* __restrict__ owh, const float* __restrict__ o_b,
    float* __restrict__ outf)
{
  const int id = blockIdx.x;
  const int m0 = ((id & 7) * 8 + ((id >> 3) & 7)) * 64;
  const int n0 = (id >> 6) * 64;

  __shared__ __align__(16) ushort AH[2][4096];
  __shared__ __align__(16) ushort BH[2][4096];

  const int t    = threadIdx.x;
  const int lane = t & 63;
  const int w    = t >> 6;
  const int wm   = w >> 1, wn = w & 1;
  const int lr   = lane & 15, lg = lane >> 4;

  const int rl  = lane >> 3;
  const int c8s = (lane & 7) ^ rl;

  // B staging: 8 chunks of 1KB via gload_lds
  auto stageB = [&](int buf, int k0){
    #pragma unroll
    for (int j = 0; j < 2; j++){
      const int c = w*2 + j;
      gload16(owh + (size_t)(n0 + c*8 + rl)*512 + k0 + c8s*8, &BH[buf][c*512]);
    }
  };

  // A staging: thread t owns row ar = t>>2, 16-col chunk ac = t&3
  const int ar = t >> 2, ac = t & 3;
  uint4v la0, la1, lb0, lb1;
  auto issueA = [&](int k0){
    const size_t base = (size_t)(m0 + ar)*512 + k0 + ac*16;
    la0 = *(const uint4v*)&Oa[base];
    la1 = *(const uint4v*)&Oa[base + 8];
    lb0 = *(const uint4v*)&Ob[base];
    lb1 = *(const uint4v*)&Ob[base + 8];
  };
  auto writeA = [&](int buf, int k0){
    const int m = m0 + ar;
    const int zq = (m >> 8)*2048 + (m & 255)*8 + (k0 >> 6);
    const float zi = 1.f / (za[zq] + zb[zq]);
    uint4v o0, o1;
    #pragma unroll
    for (int j=0;j<4;j++){
      float l0 = (b2f((ushort)(la0[j] & 0xffff)) + b2f((ushort)(lb0[j] & 0xffff))) * zi;
      float h0 = (b2f((ushort)(la0[j] >> 16))    + b2f((ushort)(lb0[j] >> 16)))    * zi;
      o0[j] = (uint)f2b(l0) | ((uint)f2b(h0) << 16);
      float l1 = (b2f((ushort)(la1[j] & 0xffff)) + b2f((ushort)(lb1[j] & 0xffff))) * zi;
      float h1 = (b2f((ushort)(la1[j] >> 16))    + b2f((ushort)(lb1[j] >> 16)))    * zi;
      o1[j] = (uint)f2b(l1) | ((uint)f2b(h1) << 16);
    }
    const int p0 = ar*64 + (((ac*2    ) ^ (ar & 7)) << 3);
    const int p1 = ar*64 + (((ac*2 + 1) ^ (ar & 7)) << 3);
    *(uint4v*)&AH[buf][p0] = o0;
    *(uint4v*)&AH[buf][p1] = o1;
  };

  floatx4 zf; zf[0]=0.f; zf[1]=0.f; zf[2]=0.f; zf[3]=0.f;
  floatx4 acc[2][2];
  #pragma unroll
  for (int i=0;i<2;i++)
    #pragma unroll
    for (int j=0;j<2;j++) acc[i][j] = zf;

  issueA(0);
  stageB(0, 0);
  writeA(0, 0);
  __syncthreads();

  int cur = 0;
  for (int it = 0; it < 8; ++it){
    if (it < 7){ issueA((it+1)*64); stageB(cur^1, (it+1)*64); }

    #pragma unroll
    for (int ks=0; ks<2; ks++){
      const int xo = ((ks*4 + lg) ^ (lr & 7)) << 3;
      bf16x8 ah[2], bh[2];
      #pragma unroll
      for (int mi=0;mi<2;mi++)
        ah[mi] = *(const bf16x8*)&AH[cur][(wm*32 + mi*16 + lr)*64 + xo];
      #pragma unroll
      for (int ni=0;ni<2;ni++)
        bh[ni] = *(const bf16x8*)&BH[cur][(wn*32 + ni*16 + lr)*64 + xo];
      #pragma unroll
      for (int mi=0;mi<2;mi++)
        #pragma unroll
        for (int ni=0;ni<2;ni++)
          acc[mi][ni] = MFMA16(ah[mi], bh[ni], acc[mi][ni]);
    }
    if (it < 7) writeA(cur^1, (it+1)*64);
    __syncthreads();
    cur ^= 1;
  }

  #pragma unroll
  for (int ni=0;ni<2;ni++){
    const int n = n0 + wn*32 + ni*16 + lr;
    const float bn = o_b[n];
    #pragma unroll
    for (int mi=0;mi<2;mi++){
      #pragma unroll
      for (int r=0;r<4;r++){
        const int m = m0 + wm*32 + mi*16 + lg*4 + r;
        outf[(size_t)m*512 + n] = acc[mi][ni][r] + bn;
      }
    }
  }
}

// ---------------------------------------------------------------------------
extern "C" void kernel_launch(void* const* d_in, const int* in_sizes, int n_in,
                              void* d_out, int out_size, void* d_ws, size_t ws_size,
                              hipStream_t stream)
{
  const float* x   = (const float*)d_in[0];
  const float* y   = (const float*)d_in[1];
  const float* q_w = (const float*)d_in[2];
  const float* q_b = (const float*)d_in[3];
  const float* k_w = (const float*)d_in[4];
  const float* k_b = (const float*)d_in[5];
  const float* v_w = (const float*)d_in[6];
  const float* v_b = (const float*)d_in[7];
  const float* o_w = (const float*)d_in[8];
  const float* o_b = (const float*)d_in[9];

  const size_t NE = 4096ull * 512;     // 2,097,152
  const size_t WN = 512ull * 512;      // 262,144
  ushort* p = (ushort*)d_ws;
  ushort* pq_hi = p;                   // 5 x NE: projections
  ushort* pq_lo = pq_hi + NE;
  ushort* pk_hi = pq_lo + NE;
  ushort* pk_lo = pk_hi + NE;
  ushort* pv    = pk_lo + NE;
  ushort* xhi   = pv + NE;             // 4 x NE: split inputs
  ushort* xlo   = xhi + NE;
  ushort* yhi   = xlo + NE;
  ushort* ylo   = yhi + NE;
  ushort* vtg   = xhi;                 // alias: xhi dead after proj_qkv
  ushort* Oa    = pv;                  // alias: pv dead after vtrans
  ushort* Ob    = yhi;                 // alias: yhi dead after proj_qkv
  float*  za    = (float*)ylo;         // alias: ylo dead after proj_qkv
  float*  zb    = za + 32768;
  ushort* qwh = ylo + NE;              // split weights (+ plain v/o)
  ushort* qwl = qwh + WN;
  ushort* kwh = qwl + WN;
  ushort* kwl = kwh + WN;
  ushort* vwh = kwl + WN;
  ushort* owh = vwh + WN;
  float*  ksumb = (float*)(owh + WN);

  hipMemsetAsync(ksumb, 0, 16 * 64 * sizeof(float), stream);

  split_all<<<5120, 256, 0, stream>>>(x, y, q_w, k_w, v_w, o_w,
                                      xhi, xlo, yhi, ylo,
                                      qwh, qwl, kwh, kwl, vwh, owh);
  proj_qkv<<<1536, 256, 0, stream>>>(xhi, xlo, yhi, ylo,
                                     qwh, qwl, kwh, kwl, vwh,
                                     q_b, k_b, v_b,
                                     pq_hi, pq_lo, pk_hi, pk_lo, pv, ksumb);
  vtrans<<<dim3(32,16), 256, 0, stream>>>(pv, vtg);
  attn_kernel<<<512, 512, 0, stream>>>(pq_hi, pq_lo, pk_hi, pk_lo, vtg, ksumb,
                                       Oa, Ob, za, zb);
  proj_out<<<512, 256, 0, stream>>>(Oa, Ob, za, zb, owh, o_b, (float*)d_out);
}